// Round 8
// baseline (101.154 us; speedup 1.0000x reference)
//
#include <hip/hip_runtime.h>
#include <math.h>

#define NN 50000
#define BB 32
#define KK 32
#define TN 64   // nodes per block in prep kernel
#define GN 8    // nodes per block in gather kernel (NN % GN == 0)

// sqrt(log2(e)): ws,g pre-scaled by this so sum(d^2) is already in log2
// units -> exp2(-acc) == exp(-d2_true). (lrelu commutes with pos. scale.)
#define SCL 1.2011224087864498f

typedef __attribute__((ext_vector_type(2))) _Float16 half2_t;
typedef __attribute__((ext_vector_type(8))) _Float16 half8_t;

// __builtin_shufflevector needs literal indices -> hand-unrolled extractors.
// Broadcast g-dword j across all 4 dwords of a half8.
__device__ __forceinline__ half8_t dup0(half8_t v) {
    return __builtin_shufflevector(v, v, 0, 1, 0, 1, 0, 1, 0, 1);
}
__device__ __forceinline__ half8_t dup1(half8_t v) {
    return __builtin_shufflevector(v, v, 2, 3, 2, 3, 2, 3, 2, 3);
}
__device__ __forceinline__ half8_t dup2(half8_t v) {
    return __builtin_shufflevector(v, v, 4, 5, 4, 5, 4, 5, 4, 5);
}
__device__ __forceinline__ half8_t splat8(float f) {
    _Float16 h = (_Float16)f;
    half8_t r;
    r[0] = h; r[1] = h; r[2] = h; r[3] = h;
    r[4] = h; r[5] = h; r[6] = h; r[7] = h;
    return r;
}

// Prep: store what gather needs to RECOMPUTE f on the fly, in fp16:
//   xT[n][b]  = (f16)x[b,n], b ascending           (64 B/node row)
//   gh[n]     = half8: dwords = (G0,G0),(G1,G1),(G2,G2),(0,0), G=SCL*g
// g[j] = sum_e emb[n,e]*W[j,e] + bias[j]. Random-gather working set:
// 3.2 + 0.8 = 4 MB (L2-resident -- R2 showed 12.8MB spills L2, 147MB fetch).
__global__ __launch_bounds__(256) void prep_kernel(
    const float* __restrict__ x,      // (B,N)
    const float* __restrict__ emb,    // (N,6)
    const float* __restrict__ W,      // (3,6)
    const float* __restrict__ bias,   // (3,)
    half2_t* __restrict__ xT,         // (N,16) b-pairs
    half8_t* __restrict__ gh)         // (N)
{
    __shared__ float xs[BB][TN + 1];  // +1 pad: transpose read conflict-free

    const int n0 = blockIdx.x * TN;
    const int t  = threadIdx.x;

#pragma unroll
    for (int j = 0; j < 8; ++j) {
        int idx = j * 256 + t;        // 0..2047
        int r = idx >> 6, c = idx & 63;
        int n = n0 + c;
        xs[r][c] = (n < NN) ? x[r * NN + n] : 0.f;
    }
    __syncthreads();

#pragma unroll
    for (int it = 0; it < 4; ++it) {
        int slot = it * 256 + t;      // 0..1023
        int nl = slot >> 4, b2 = slot & 15;
        int n = n0 + nl;
        if (n < NN) {
            half2_t p;
            p.x = (_Float16)xs[2 * b2][nl];
            p.y = (_Float16)xs[2 * b2 + 1][nl];
            xT[n * 16 + b2] = p;                // 16 lanes -> 64B contiguous
            if (b2 == 0) {
                float e[6];
#pragma unroll
                for (int q = 0; q < 6; ++q) e[q] = emb[n * 6 + q];
                half8_t gv;
#pragma unroll
                for (int j = 0; j < 3; ++j) {
                    float s = bias[j];
#pragma unroll
                    for (int q = 0; q < 6; ++q) s += e[q] * W[j * 6 + q];
                    s *= SCL;
                    gv[2 * j] = (_Float16)s;
                    gv[2 * j + 1] = (_Float16)s;
                }
                gv[6] = (_Float16)0.f; gv[7] = (_Float16)0.f;
                gh[n] = gv;
            }
        }
    }
}

// Gather: block = 8 nodes (grid 6250). 64 subgroups of 4 lanes; subgroup
// sg owns node (sg>>3) and k-range (sg&7)*4..+3; lane l holds b = 8l..8l+7
// as one half8 (4 pk-insts per vector op). vs R7: 16 pairs/wave-iter (was
// 8) -> ds_read/addr/load/reduce cost per pair halved; exp2 (pre-scaled
// ws,g) drops the per-exp multiply.
__global__ __launch_bounds__(256) void gather_kernel(
    const half8_t* __restrict__ xT8,  // (N,4) viewed as half8
    const half8_t* __restrict__ gh,   // (N)
    const float* __restrict__ W,      // (3,6)
    const int* __restrict__ nbr,      // (N,K)
    float* __restrict__ out)          // (N,K)
{
    __shared__ int nbr_sh[GN * KK];   // 8 nodes x 32 k = 256

    const int t  = threadIdx.x;
    const int n0 = blockIdx.x * GN;

    nbr_sh[t] = nbr[n0 * KK + t];
    __syncthreads();

    // ws[j] = SCL * sum_e W[j,e], splat across half8.
    half8_t ws8[3];
#pragma unroll
    for (int j = 0; j < 3; ++j) {
        float s = 0.f;
#pragma unroll
        for (int q = 0; q < 6; ++q) s += W[j * 6 + q];
        ws8[j] = splat8(s * SCL);
    }
    const half8_t lk = splat8(0.2f);

    const int l  = t & 3;             // lane in subgroup
    const int sg = t >> 2;            // 0..63
    const int nl = sg >> 3;           // node local 0..7
    const int kb = (sg & 7) * 4;      // k base
    const int n  = n0 + nl;

    // Center features for this lane's 8 b's (registers, once per subgroup).
    half8_t xn8 = xT8[n * 4 + l];     // 16B/lane, 64B/row coalesced
    half8_t gn8 = gh[n];
    half8_t fn0, fn1, fn2;
    {
        half8_t u;
        u = xn8 * ws8[0] + dup0(gn8); fn0 = __builtin_elementwise_max(u, u * lk);
        u = xn8 * ws8[1] + dup1(gn8); fn1 = __builtin_elementwise_max(u, u * lk);
        u = xn8 * ws8[2] + dup2(gn8); fn2 = __builtin_elementwise_max(u, u * lk);
    }

    const int mb = nl * KK + kb;

#pragma unroll
    for (int i = 0; i < 4; ++i) {
        int m  = nbr_sh[mb + i];      // per-subgroup broadcast ds_read
        int mc = m > 0 ? m : 0;
        half8_t xm8 = xT8[mc * 4 + l];          // 16B/lane
        half8_t gm8 = gh[mc];                   // 16B broadcast per subgroup

        half8_t acc = splat8(0.f);
        {
            half8_t u, d;
            u = xm8 * ws8[0] + dup0(gm8);
            u = __builtin_elementwise_max(u, u * lk);
            d = fn0 - u; acc = d * d + acc;
            u = xm8 * ws8[1] + dup1(gm8);
            u = __builtin_elementwise_max(u, u * lk);
            d = fn1 - u; acc = d * d + acc;
            u = xm8 * ws8[2] + dup2(gm8);
            u = __builtin_elementwise_max(u, u * lk);
            d = fn2 - u; acc = d * d + acc;
        }
        // acc is in log2 units (SCL^2 folded) -> plain exp2.
        float v = (exp2f(-(float)acc[0]) + exp2f(-(float)acc[1]))
                + (exp2f(-(float)acc[2]) + exp2f(-(float)acc[3]))
                + (exp2f(-(float)acc[4]) + exp2f(-(float)acc[5]))
                + (exp2f(-(float)acc[6]) + exp2f(-(float)acc[7]));
        v += __shfl_down(v, 2, 4);
        v += __shfl_down(v, 1, 4);
        if (l == 0) out[n * KK + kb + i] = (m < 0) ? 0.f : v * (1.0f / 32.0f);
    }
}

extern "C" void kernel_launch(void* const* d_in, const int* in_sizes, int n_in,
                              void* d_out, int out_size, void* d_ws, size_t ws_size,
                              hipStream_t stream) {
    const float* x    = (const float*)d_in[0];
    const float* emb  = (const float*)d_in[1];
    const float* W    = (const float*)d_in[2];
    const float* bias = (const float*)d_in[3];
    const int*   nbr  = (const int*)d_in[4];
    float* out = (float*)d_out;

    half2_t* xT = (half2_t*)d_ws;                              // 3.2 MB
    half8_t* gh = (half8_t*)((char*)d_ws + NN * 16 * sizeof(half2_t)); // 0.8 MB

    prep_kernel<<<(NN + TN - 1) / TN, 256, 0, stream>>>(x, emb, W, bias, xT, gh);
    gather_kernel<<<NN / GN, 256, 0, stream>>>((const half8_t*)xT, gh, W, nbr, out);
}